// Round 1
// baseline (114.401 us; speedup 1.0000x reference)
//
#include <hip/hip_runtime.h>
#include <math.h>

// Problem constants (fixed by setup_inputs)
#define Bn   4
#define Kn   32
#define Dn   512
#define Nn   4096
#define AGS  64     // sqrt(N)
#define RES  512    // mask resolution
#define TS   16     // patch output size
// linspace(-0.125, 0.125, 16) step
#define OFF0   (-0.125f)
#define OFFSTEP (0.25f / 15.0f)

__device__ __forceinline__ float unnorm_clip(float g, float size) {
    float v = ((g + 1.0f) * size - 1.0f) * 0.5f;
    return fminf(fmaxf(v, 0.0f), size - 1.0f);
}

// --- 1. confidence: elementwise over B*K*64*64 ---
__global__ void conf_kernel(const float* __restrict__ logits,
                            float* __restrict__ out, int n) {
    int i = blockIdx.x * blockDim.x + threadIdx.x;
    if (i >= n) return;
    float x = logits[i] * (1.0f / 1.5f);
    float p = 1.0f / (1.0f + expf(-x));
    p = fminf(fmaxf(p, 1e-6f), 1.0f - 1e-6f);
    float ent = -(p * logf(p) + (1.0f - p) * logf(1.0f - p));
    out[i] = 1.0f - ent * 1.4426950408889634f;  // 1/ln(2)
}

// --- 2. mask patches: one thread per (b,k,i,j) ---
__global__ void mask_kernel(const float* __restrict__ mask,
                            const int* __restrict__ coords,
                            float* __restrict__ out) {
    int idx = blockIdx.x * blockDim.x + threadIdx.x;
    if (idx >= Bn * Kn * TS * TS) return;
    int j  = idx & 15;
    int i  = (idx >> 4) & 15;
    int bk = idx >> 8;            // b*K + k
    int b  = bk >> 5;             // / K

    float ch = (float)coords[bk * 2 + 0];
    float cw = (float)coords[bk * 2 + 1];
    // centers: cy from ch+32, cx from cw+32, normalized by RES
    float cy = (ch + 32.0f) * (2.0f / 512.0f) - 1.0f;
    float cx = (cw + 32.0f) * (2.0f / 512.0f) - 1.0f;
    float gx = cx + (OFF0 + j * OFFSTEP);
    float gy = cy + (OFF0 + i * OFFSTEP);

    float x = unnorm_clip(gx, 512.0f);
    float y = unnorm_clip(gy, 512.0f);
    float x0f = floorf(x), y0f = floorf(y);
    int x0 = (int)x0f, y0 = (int)y0f;
    int x1 = min(x0 + 1, 511), y1 = min(y0 + 1, 511);
    float wx = x - x0f, wy = y - y0f;

    const float* mb = mask + (size_t)b * RES * RES;
    float v00 = mb[y0 * RES + x0];
    float v01 = mb[y0 * RES + x1];
    float v10 = mb[y1 * RES + x0];
    float v11 = mb[y1 * RES + x1];
    float top = v00 * (1.0f - wx) + v01 * wx;
    float bot = v10 * (1.0f - wx) + v11 * wx;
    out[idx] = top * (1.0f - wy) + bot * wy;
}

// --- 3. patch features: thread = (sample, d-chunk of 4); 128 threads/sample ---
__global__ void feat_kernel(const float* __restrict__ features,
                            const int* __restrict__ coords,
                            float* __restrict__ out) {
    int tid = blockIdx.x * blockDim.x + threadIdx.x;
    int dc     = tid & 127;       // float4 index within D=512
    int sample = tid >> 7;        // (b*K+k)*256 + i*16 + j
    if (sample >= Bn * Kn * TS * TS) return;
    int j  = sample & 15;
    int i  = (sample >> 4) & 15;
    int bk = sample >> 8;
    int b  = bk >> 5;

    float ch = (float)coords[bk * 2 + 0];
    float cw = (float)coords[bk * 2 + 1];
    // feature grid: fh = ch*scale + psf/2 = ch*0.125 + 4, res = ags = 64
    float cy = (ch * 0.125f + 4.0f) * (2.0f / 64.0f) - 1.0f;
    float cx = (cw * 0.125f + 4.0f) * (2.0f / 64.0f) - 1.0f;
    float gx = cx + (OFF0 + j * OFFSTEP);
    float gy = cy + (OFF0 + i * OFFSTEP);

    float x = unnorm_clip(gx, 64.0f);
    float y = unnorm_clip(gy, 64.0f);
    float x0f = floorf(x), y0f = floorf(y);
    int x0 = (int)x0f, y0 = (int)y0f;
    int x1 = min(x0 + 1, 63), y1 = min(y0 + 1, 63);
    float wx = x - x0f, wy = y - y0f;

    const float4* f = (const float4*)(features + (size_t)b * Nn * Dn);
    // row stride in float4 units: D/4 = 128
    float4 v00 = f[(y0 * AGS + x0) * 128 + dc];
    float4 v01 = f[(y0 * AGS + x1) * 128 + dc];
    float4 v10 = f[(y1 * AGS + x0) * 128 + dc];
    float4 v11 = f[(y1 * AGS + x1) * 128 + dc];

    float4 top, bot, r;
    top.x = v00.x * (1.0f - wx) + v01.x * wx;
    top.y = v00.y * (1.0f - wx) + v01.y * wx;
    top.z = v00.z * (1.0f - wx) + v01.z * wx;
    top.w = v00.w * (1.0f - wx) + v01.w * wx;
    bot.x = v10.x * (1.0f - wx) + v11.x * wx;
    bot.y = v10.y * (1.0f - wx) + v11.y * wx;
    bot.z = v10.z * (1.0f - wx) + v11.z * wx;
    bot.w = v10.w * (1.0f - wx) + v11.w * wx;
    r.x = top.x * (1.0f - wy) + bot.x * wy;
    r.y = top.y * (1.0f - wy) + bot.y * wy;
    r.z = top.z * (1.0f - wy) + bot.z * wy;
    r.w = top.w * (1.0f - wy) + bot.w * wy;

    ((float4*)out)[(size_t)sample * 128 + dc] = r;
}

extern "C" void kernel_launch(void* const* d_in, const int* in_sizes, int n_in,
                              void* d_out, int out_size, void* d_ws, size_t ws_size,
                              hipStream_t stream) {
    const float* features = (const float*)d_in[0];
    const float* mask     = (const float*)d_in[1];
    const float* logits   = (const float*)d_in[2];
    const int*   coords   = (const int*)d_in[3];

    float* out_conf = (float*)d_out;                       // B*K*64*64
    float* out_mask = out_conf + (size_t)Bn * Kn * 64 * 64; // B*K*16*16
    float* out_feat = out_mask + (size_t)Bn * Kn * TS * TS; // B*K*256*D

    int n_conf = Bn * Kn * 64 * 64;                        // 524288
    conf_kernel<<<(n_conf + 255) / 256, 256, 0, stream>>>(logits, out_conf, n_conf);

    int n_mask = Bn * Kn * TS * TS;                        // 32768
    mask_kernel<<<(n_mask + 255) / 256, 256, 0, stream>>>(mask, coords, out_mask);

    int n_feat_threads = Bn * Kn * TS * TS * 128;          // 4194304
    feat_kernel<<<(n_feat_threads + 255) / 256, 256, 0, stream>>>(features, coords, out_feat);
}

// Round 3
// 113.208 us; speedup vs baseline: 1.0105x; 1.0105x over previous
//
#include <hip/hip_runtime.h>
#include <math.h>

// Problem constants (fixed by setup_inputs)
#define Bn   4
#define Kn   32
#define Dn   512
#define Nn   4096
#define AGS  64     // sqrt(N)
#define RES  512    // mask resolution
#define TS   16     // patch output size
// linspace(-0.125, 0.125, 16) step
#define OFF0    (-0.125f)
#define OFFSTEP (0.25f / 15.0f)

typedef float f32x4 __attribute__((ext_vector_type(4)));

// fused-kernel thread ranges
#define FEAT_T (Bn * Kn * TS * TS * 64)      // 64 threads/sample, 2 float4 each = 2,097,152
#define CONF_T (Bn * Kn * 64 * 64 / 4)       // float4-vectorized               =   131,072
#define MASK_T (Bn * Kn * TS * TS)           //                                 =    32,768
#define TOTAL_T (FEAT_T + CONF_T + MASK_T)   // 2,260,992 (divisible by 256)

__device__ __forceinline__ float unnorm_clip(float g, float size) {
    float v = ((g + 1.0f) * size - 1.0f) * 0.5f;
    return fminf(fmaxf(v, 0.0f), size - 1.0f);
}

__device__ __forceinline__ float conf_elem(float logit) {
    // s = logit/T; p = sigmoid(s); ent = ln(1+e^-s) + (1-p)*s ; conf = 1 - ent/ln2
    float s = logit * (1.0f / 1.5f);
    float e = __expf(-s);
    float p = 1.0f / (1.0f + e);
    float ent = __logf(1.0f + e) + (1.0f - p) * s;
    return 1.0f - ent * 1.4426950408889634f;
}

__global__ __launch_bounds__(256) void fused_kernel(
    const float* __restrict__ features,
    const float* __restrict__ mask,
    const float* __restrict__ logits,
    const int*   __restrict__ coords,
    float* __restrict__ out_conf,
    float* __restrict__ out_mask,
    float* __restrict__ out_feat) {

    int tid = blockIdx.x * blockDim.x + threadIdx.x;

    if (tid < FEAT_T) {
        // ---- patch features: 64 threads per sample, 2 float4 per thread ----
        int dc     = tid & 63;        // float4 index base within D/4=128
        int sample = tid >> 6;        // bk*256 + i*16 + j
        int j  = sample & 15;
        int i  = (sample >> 4) & 15;
        int bk = sample >> 8;
        int b  = bk >> 5;

        float ch = (float)coords[bk * 2 + 0];
        float cw = (float)coords[bk * 2 + 1];
        // feature grid: center = c*0.125 + 4 on a 64-res grid
        float cy = (ch * 0.125f + 4.0f) * (2.0f / 64.0f) - 1.0f;
        float cx = (cw * 0.125f + 4.0f) * (2.0f / 64.0f) - 1.0f;
        float gx = cx + (OFF0 + j * OFFSTEP);
        float gy = cy + (OFF0 + i * OFFSTEP);

        float x = unnorm_clip(gx, 64.0f);
        float y = unnorm_clip(gy, 64.0f);
        float x0f = floorf(x), y0f = floorf(y);
        int x0 = (int)x0f, y0 = (int)y0f;
        int x1 = min(x0 + 1, 63), y1 = min(y0 + 1, 63);
        float wx = x - x0f, wy = y - y0f;

        const f32x4* f = (const f32x4*)(features + (size_t)b * Nn * Dn);
        int r00 = (y0 * AGS + x0) * 128 + dc;
        int r01 = (y0 * AGS + x1) * 128 + dc;
        int r10 = (y1 * AGS + x0) * 128 + dc;
        int r11 = (y1 * AGS + x1) * 128 + dc;

        // 8 independent loads in flight
        f32x4 a00 = f[r00],      a01 = f[r01],      a10 = f[r10],      a11 = f[r11];
        f32x4 b00 = f[r00 + 64], b01 = f[r01 + 64], b10 = f[r10 + 64], b11 = f[r11 + 64];

        float w00 = (1.0f - wx) * (1.0f - wy);
        float w01 = wx * (1.0f - wy);
        float w10 = (1.0f - wx) * wy;
        float w11 = wx * wy;

        f32x4 ra = a00 * w00 + a01 * w01 + a10 * w10 + a11 * w11;
        f32x4 rb = b00 * w00 + b01 * w01 + b10 * w10 + b11 * w11;

        f32x4* op = (f32x4*)out_feat + (size_t)sample * 128 + dc;
        __builtin_nontemporal_store(ra, op);
        __builtin_nontemporal_store(rb, op + 64);
        return;
    }
    tid -= FEAT_T;

    if (tid < CONF_T) {
        // ---- confidence: float4-vectorized elementwise ----
        f32x4 v = ((const f32x4*)logits)[tid];
        f32x4 r;
        r.x = conf_elem(v.x);
        r.y = conf_elem(v.y);
        r.z = conf_elem(v.z);
        r.w = conf_elem(v.w);
        __builtin_nontemporal_store(r, (f32x4*)out_conf + tid);
        return;
    }
    tid -= CONF_T;

    {
        // ---- mask patches: one thread per (b,k,i,j) ----
        int idx = tid;
        int j  = idx & 15;
        int i  = (idx >> 4) & 15;
        int bk = idx >> 8;
        int b  = bk >> 5;

        float ch = (float)coords[bk * 2 + 0];
        float cw = (float)coords[bk * 2 + 1];
        float cy = (ch + 32.0f) * (2.0f / 512.0f) - 1.0f;
        float cx = (cw + 32.0f) * (2.0f / 512.0f) - 1.0f;
        float gx = cx + (OFF0 + j * OFFSTEP);
        float gy = cy + (OFF0 + i * OFFSTEP);

        float x = unnorm_clip(gx, 512.0f);
        float y = unnorm_clip(gy, 512.0f);
        float x0f = floorf(x), y0f = floorf(y);
        int x0 = (int)x0f, y0 = (int)y0f;
        int x1 = min(x0 + 1, 511), y1 = min(y0 + 1, 511);
        float wx = x - x0f, wy = y - y0f;

        const float* mb = mask + (size_t)b * RES * RES;
        float v00 = mb[y0 * RES + x0];
        float v01 = mb[y0 * RES + x1];
        float v10 = mb[y1 * RES + x0];
        float v11 = mb[y1 * RES + x1];
        float top = v00 * (1.0f - wx) + v01 * wx;
        float bot = v10 * (1.0f - wx) + v11 * wx;
        float r = top * (1.0f - wy) + bot * wy;
        __builtin_nontemporal_store(r, out_mask + idx);
    }
}

extern "C" void kernel_launch(void* const* d_in, const int* in_sizes, int n_in,
                              void* d_out, int out_size, void* d_ws, size_t ws_size,
                              hipStream_t stream) {
    const float* features = (const float*)d_in[0];
    const float* mask     = (const float*)d_in[1];
    const float* logits   = (const float*)d_in[2];
    const int*   coords   = (const int*)d_in[3];

    float* out_conf = (float*)d_out;                        // B*K*64*64
    float* out_mask = out_conf + (size_t)Bn * Kn * 64 * 64; // B*K*16*16
    float* out_feat = out_mask + (size_t)Bn * Kn * TS * TS; // B*K*256*D

    fused_kernel<<<TOTAL_T / 256, 256, 0, stream>>>(
        features, mask, logits, coords, out_conf, out_mask, out_feat);
}

// Round 4
// 112.795 us; speedup vs baseline: 1.0142x; 1.0037x over previous
//
#include <hip/hip_runtime.h>
#include <math.h>

// Problem constants (fixed by setup_inputs)
#define Bn   4
#define Kn   32
#define Dn   512
#define Nn   4096
#define AGS  64     // sqrt(N)
#define RES  512    // mask resolution
#define TS   16     // patch output size
// linspace(-0.125, 0.125, 16) step
#define OFF0    (-0.125f)
#define OFFSTEP (0.25f / 15.0f)

typedef float f32x4 __attribute__((ext_vector_type(4)));

// fused-kernel thread ranges
#define FEAT_T (Bn * Kn * TS * TS * 64)      // 64 threads/sample, 2 float4 each = 2,097,152
#define CONF_T (Bn * Kn * 64 * 64 / 4)       // float4-vectorized               =   131,072
#define MASK_T (Bn * Kn * TS * TS)           //                                 =    32,768
#define TOTAL_T (FEAT_T + CONF_T + MASK_T)   // 2,260,992 = 8832 blocks of 256

// XCD swizzle: group = 64 blocks = exactly one patch's feat work (16384 threads).
// 8832 blocks = 138 groups; pad to 144 groups (grid 9216) so groups round-robin
// bijectively across the 8 XCDs: group g -> XCD g%8, consecutive blocks of a
// group sit at consecutive per-XCD slots (hw round-robin b -> XCD b&7).
#define GROUP_BLKS 64
#define GROUPS_PAD 144
#define GRID_BLKS  (GROUPS_PAD * GROUP_BLKS)   // 9216

__device__ __forceinline__ float unnorm_clip(float g, float size) {
    float v = ((g + 1.0f) * size - 1.0f) * 0.5f;
    return fminf(fmaxf(v, 0.0f), size - 1.0f);
}

__device__ __forceinline__ float conf_elem(float logit) {
    // s = logit/T; p = sigmoid(s); ent = ln(1+e^-s) + (1-p)*s ; conf = 1 - ent/ln2
    float s = logit * (1.0f / 1.5f);
    float e = __expf(-s);
    float p = 1.0f / (1.0f + e);
    float ent = __logf(1.0f + e) + (1.0f - p) * s;
    return 1.0f - ent * 1.4426950408889634f;
}

__global__ __launch_bounds__(256) void fused_kernel(
    const float* __restrict__ features,
    const float* __restrict__ mask,
    const float* __restrict__ logits,
    const int*   __restrict__ coords,
    float* __restrict__ out_conf,
    float* __restrict__ out_mask,
    float* __restrict__ out_feat) {

    // ---- XCD-chunked swizzle: keep each patch's 64 blocks on one XCD ----
    int b   = blockIdx.x;          // 0..9215
    int xcd = b & 7;
    int p   = b >> 3;              // per-XCD slot, 0..1151
    int g   = xcd + ((p >> 6) << 3);          // group 0..143, g%8 == xcd
    int wb  = (g << 6) | (p & 63);            // work block
    int tid = wb * 256 + (int)threadIdx.x;
    if (tid >= TOTAL_T) return;               // pad groups + tail

    if (tid < FEAT_T) {
        // ---- patch features: 64 threads per sample, 2 float4 per thread ----
        int dc     = tid & 63;        // float4 index base within D/4=128
        int sample = tid >> 6;        // bk*256 + i*16 + j
        int j  = sample & 15;
        int i  = (sample >> 4) & 15;
        int bk = sample >> 8;
        int bb = bk >> 5;

        float ch = (float)coords[bk * 2 + 0];
        float cw = (float)coords[bk * 2 + 1];
        // feature grid: center = c*0.125 + 4 on a 64-res grid
        float cy = (ch * 0.125f + 4.0f) * (2.0f / 64.0f) - 1.0f;
        float cx = (cw * 0.125f + 4.0f) * (2.0f / 64.0f) - 1.0f;
        float gx = cx + (OFF0 + j * OFFSTEP);
        float gy = cy + (OFF0 + i * OFFSTEP);

        float x = unnorm_clip(gx, 64.0f);
        float y = unnorm_clip(gy, 64.0f);
        float x0f = floorf(x), y0f = floorf(y);
        int x0 = (int)x0f, y0 = (int)y0f;
        int x1 = min(x0 + 1, 63), y1 = min(y0 + 1, 63);
        float wx = x - x0f, wy = y - y0f;

        const f32x4* f = (const f32x4*)(features + (size_t)bb * Nn * Dn);
        int r00 = (y0 * AGS + x0) * 128 + dc;
        int r01 = (y0 * AGS + x1) * 128 + dc;
        int r10 = (y1 * AGS + x0) * 128 + dc;
        int r11 = (y1 * AGS + x1) * 128 + dc;

        // 8 independent loads in flight
        f32x4 a00 = f[r00],      a01 = f[r01],      a10 = f[r10],      a11 = f[r11];
        f32x4 b00 = f[r00 + 64], b01 = f[r01 + 64], b10 = f[r10 + 64], b11 = f[r11 + 64];

        float w00 = (1.0f - wx) * (1.0f - wy);
        float w01 = wx * (1.0f - wy);
        float w10 = (1.0f - wx) * wy;
        float w11 = wx * wy;

        f32x4 ra = a00 * w00 + a01 * w01 + a10 * w10 + a11 * w11;
        f32x4 rb = b00 * w00 + b01 * w01 + b10 * w10 + b11 * w11;

        f32x4* op = (f32x4*)out_feat + (size_t)sample * 128 + dc;
        __builtin_nontemporal_store(ra, op);
        __builtin_nontemporal_store(rb, op + 64);
        return;
    }
    tid -= FEAT_T;

    if (tid < CONF_T) {
        // ---- confidence: float4-vectorized elementwise ----
        f32x4 v = ((const f32x4*)logits)[tid];
        f32x4 r;
        r.x = conf_elem(v.x);
        r.y = conf_elem(v.y);
        r.z = conf_elem(v.z);
        r.w = conf_elem(v.w);
        __builtin_nontemporal_store(r, (f32x4*)out_conf + tid);
        return;
    }
    tid -= CONF_T;

    {
        // ---- mask patches: one thread per (b,k,i,j) ----
        int idx = tid;
        int j  = idx & 15;
        int i  = (idx >> 4) & 15;
        int bk = idx >> 8;
        int bb = bk >> 5;

        float ch = (float)coords[bk * 2 + 0];
        float cw = (float)coords[bk * 2 + 1];
        float cy = (ch + 32.0f) * (2.0f / 512.0f) - 1.0f;
        float cx = (cw + 32.0f) * (2.0f / 512.0f) - 1.0f;
        float gx = cx + (OFF0 + j * OFFSTEP);
        float gy = cy + (OFF0 + i * OFFSTEP);

        float x = unnorm_clip(gx, 512.0f);
        float y = unnorm_clip(gy, 512.0f);
        float x0f = floorf(x), y0f = floorf(y);
        int x0 = (int)x0f, y0 = (int)y0f;
        int x1 = min(x0 + 1, 511), y1 = min(y0 + 1, 511);
        float wx = x - x0f, wy = y - y0f;

        const float* mb = mask + (size_t)bb * RES * RES;
        float v00 = mb[y0 * RES + x0];
        float v01 = mb[y0 * RES + x1];
        float v10 = mb[y1 * RES + x0];
        float v11 = mb[y1 * RES + x1];
        float top = v00 * (1.0f - wx) + v01 * wx;
        float bot = v10 * (1.0f - wx) + v11 * wx;
        float r = top * (1.0f - wy) + bot * wy;
        __builtin_nontemporal_store(r, out_mask + idx);
    }
}

extern "C" void kernel_launch(void* const* d_in, const int* in_sizes, int n_in,
                              void* d_out, int out_size, void* d_ws, size_t ws_size,
                              hipStream_t stream) {
    const float* features = (const float*)d_in[0];
    const float* mask     = (const float*)d_in[1];
    const float* logits   = (const float*)d_in[2];
    const int*   coords   = (const int*)d_in[3];

    float* out_conf = (float*)d_out;                        // B*K*64*64
    float* out_mask = out_conf + (size_t)Bn * Kn * 64 * 64; // B*K*16*16
    float* out_feat = out_mask + (size_t)Bn * Kn * TS * TS; // B*K*256*D

    fused_kernel<<<GRID_BLKS, 256, 0, stream>>>(
        features, mask, logits, coords, out_conf, out_mask, out_feat);
}

// Round 6
// 105.223 us; speedup vs baseline: 1.0872x; 1.0720x over previous
//
#include <hip/hip_runtime.h>
#include <math.h>

// Problem constants (fixed by setup_inputs)
#define Bn   4
#define Kn   32
#define Dn   512
#define Nn   4096
#define AGS  64     // sqrt(N)
#define RES  512    // mask resolution
#define TS   16     // patch output size
// linspace(-0.125, 0.125, 16) step
#define OFF0    (-0.125f)
#define OFFSTEP (0.25f / 15.0f)

typedef float f32x4 __attribute__((ext_vector_type(4)));

// Workgroup plan (all 256 threads):
//   feat: 128 patches x 4 D-chunks = 512 WGs. Each stages the patch's 10x10
//         feature-pixel window (its 128-float chunk) into 50KB LDS, then
//         computes 256 samples x 32 float4 from LDS.
//   conf: 512 WGs, float4-elementwise.
//   mask: 128 WGs, 1 sample/thread.
#define FEAT_WGS 512
#define CONF_WGS 512
#define MASK_WGS 128
#define NWG (FEAT_WGS + CONF_WGS + MASK_WGS)   // 1152

__device__ __forceinline__ float unnorm_clip(float g, float size) {
    float v = ((g + 1.0f) * size - 1.0f) * 0.5f;
    return fminf(fmaxf(v, 0.0f), size - 1.0f);
}

__device__ __forceinline__ float conf_elem(float logit) {
    float s = logit * (1.0f / 1.5f);
    float e = __expf(-s);
    float p = 1.0f / (1.0f + e);
    float ent = __logf(1.0f + e) + (1.0f - p) * s;
    return 1.0f - ent * 1.4426950408889634f;  // 1/ln2
}

__global__ __launch_bounds__(256) void fused_kernel(
    const float* __restrict__ features,
    const float* __restrict__ mask,
    const float* __restrict__ logits,
    const int*   __restrict__ coords,
    float* __restrict__ out_conf,
    float* __restrict__ out_mask,
    float* __restrict__ out_feat) {

    // 10x10 window x 32 float4 per pixel = 51200 B
    __shared__ f32x4 tile[100 * 32];

    int wg = blockIdx.x;
    int t  = threadIdx.x;

    if (wg < FEAT_WGS) {
        int bk     = wg >> 2;        // patch 0..127
        int dchunk = wg & 3;         // D-chunk: float4s [dchunk*32, dchunk*32+32)
        int b      = bk >> 5;

        float ch = (float)coords[bk * 2 + 0];
        float cw = (float)coords[bk * 2 + 1];
        float fh = ch * 0.125f + 4.0f;   // row center in feature px
        float fw = cw * 0.125f + 4.0f;   // col center in feature px
        // sample x,y always lie in [f-4.5, f+3.5] before clipping -> a 10-px
        // window starting at clamp(floor(f-4.5), 0, 54) covers x0 and x1.
        int r0 = min(max((int)floorf(fh - 4.5f), 0), AGS - 10);
        int c0 = min(max((int)floorf(fw - 4.5f), 0), AGS - 10);

        // ---- stage 100 px x 512B into LDS (8 px per iter, 32 lanes/px) ----
        const f32x4* fsrc = (const f32x4*)(features + (size_t)b * Nn * Dn);
        int lane = t & 31;           // float4 within chunk
        int slot = t >> 5;           // 0..7
        #pragma unroll
        for (int it = 0; it < 13; ++it) {
            int px = it * 8 + slot;
            if (px < 100) {
                int r = px / 10;
                int c = px - r * 10;
                tile[px * 32 + lane] =
                    fsrc[(size_t)((r0 + r) * AGS + (c0 + c)) * 128 + dchunk * 32 + lane];
            }
        }
        __syncthreads();

        // ---- compute: thread = (slot, lane); 32 samples per thread ----
        float cyn = fh * (2.0f / 64.0f) - 1.0f;
        float cxn = fw * (2.0f / 64.0f) - 1.0f;
        f32x4* outp = (f32x4*)out_feat + (size_t)bk * 256 * 128 + dchunk * 32 + lane;

        for (int s = 0; s < 32; ++s) {
            int sl = slot + (s << 3);      // sample 0..255
            int i = sl >> 4, j = sl & 15;
            float gx = cxn + (OFF0 + j * OFFSTEP);
            float gy = cyn + (OFF0 + i * OFFSTEP);
            float x = unnorm_clip(gx, 64.0f);
            float y = unnorm_clip(gy, 64.0f);
            float x0f = floorf(x), y0f = floorf(y);
            int x0 = (int)x0f, y0 = (int)y0f;
            int x1 = min(x0 + 1, 63), y1 = min(y0 + 1, 63);
            float wx = x - x0f, wy = y - y0f;
            int xi0 = x0 - c0, xi1 = x1 - c0;
            int yi0 = y0 - r0, yi1 = y1 - r0;

            f32x4 v00 = tile[(yi0 * 10 + xi0) * 32 + lane];
            f32x4 v01 = tile[(yi0 * 10 + xi1) * 32 + lane];
            f32x4 v10 = tile[(yi1 * 10 + xi0) * 32 + lane];
            f32x4 v11 = tile[(yi1 * 10 + xi1) * 32 + lane];

            float w00 = (1.0f - wx) * (1.0f - wy);
            float w01 = wx * (1.0f - wy);
            float w10 = (1.0f - wx) * wy;
            float w11 = wx * wy;
            f32x4 res = v00 * w00 + v01 * w01 + v10 * w10 + v11 * w11;

            __builtin_nontemporal_store(res, outp + (size_t)sl * 128);
        }
        return;
    }

    if (wg < FEAT_WGS + CONF_WGS) {
        // ---- confidence: float4-vectorized elementwise ----
        int tid = (wg - FEAT_WGS) * 256 + t;     // 0..131071
        f32x4 v = ((const f32x4*)logits)[tid];
        f32x4 r;
        r.x = conf_elem(v.x);
        r.y = conf_elem(v.y);
        r.z = conf_elem(v.z);
        r.w = conf_elem(v.w);
        __builtin_nontemporal_store(r, (f32x4*)out_conf + tid);
        return;
    }

    {
        // ---- mask patches: one thread per (b,k,i,j) ----
        int idx = (wg - FEAT_WGS - CONF_WGS) * 256 + t;  // 0..32767
        int j  = idx & 15;
        int i  = (idx >> 4) & 15;
        int bk = idx >> 8;
        int bb = bk >> 5;

        float ch = (float)coords[bk * 2 + 0];
        float cw = (float)coords[bk * 2 + 1];
        float cy = (ch + 32.0f) * (2.0f / 512.0f) - 1.0f;
        float cx = (cw + 32.0f) * (2.0f / 512.0f) - 1.0f;
        float gx = cx + (OFF0 + j * OFFSTEP);
        float gy = cy + (OFF0 + i * OFFSTEP);

        float x = unnorm_clip(gx, 512.0f);
        float y = unnorm_clip(gy, 512.0f);
        float x0f = floorf(x), y0f = floorf(y);
        int x0 = (int)x0f, y0 = (int)y0f;
        int x1 = min(x0 + 1, 511), y1 = min(y0 + 1, 511);
        float wx = x - x0f, wy = y - y0f;

        const float* mb = mask + (size_t)bb * RES * RES;
        float v00 = mb[y0 * RES + x0];
        float v01 = mb[y0 * RES + x1];
        float v10 = mb[y1 * RES + x0];
        float v11 = mb[y1 * RES + x1];
        float top = v00 * (1.0f - wx) + v01 * wx;
        float bot = v10 * (1.0f - wx) + v11 * wx;
        float r = top * (1.0f - wy) + bot * wy;
        __builtin_nontemporal_store(r, out_mask + idx);
    }
}

extern "C" void kernel_launch(void* const* d_in, const int* in_sizes, int n_in,
                              void* d_out, int out_size, void* d_ws, size_t ws_size,
                              hipStream_t stream) {
    const float* features = (const float*)d_in[0];
    const float* mask     = (const float*)d_in[1];
    const float* logits   = (const float*)d_in[2];
    const int*   coords   = (const int*)d_in[3];

    float* out_conf = (float*)d_out;                        // B*K*64*64
    float* out_mask = out_conf + (size_t)Bn * Kn * 64 * 64; // B*K*16*16
    float* out_feat = out_mask + (size_t)Bn * Kn * TS * TS; // B*K*256*D

    fused_kernel<<<NWG, 256, 0, stream>>>(
        features, mask, logits, coords, out_conf, out_mask, out_feat);
}

// Round 7
// 102.707 us; speedup vs baseline: 1.1139x; 1.0245x over previous
//
#include <hip/hip_runtime.h>
#include <math.h>

// Problem constants (fixed by setup_inputs)
#define Bn   4
#define Kn   32
#define Dn   512
#define Nn   4096
#define AGS  64     // sqrt(N)
#define RES  512    // mask resolution
#define TS   16     // patch output size
// linspace(-0.125, 0.125, 16) step
#define OFF0    (-0.125f)
#define OFFSTEP (0.25f / 15.0f)

typedef float f32x4 __attribute__((ext_vector_type(4)));

// Workgroup plan (all 256 threads):
//   feat: 128 patches x 4 D-chunks = 512 WGs. Each stages the patch's 10x10
//         feature-pixel window (its 128-float chunk) into 50KB LDS, then
//         computes 256 samples x 32 float4 from LDS.
//   conf: 512 WGs, float4-elementwise.
//   mask: 128 WGs, 1 sample/thread.
#define FEAT_WGS 512
#define CONF_WGS 512
#define MASK_WGS 128
#define NWG (FEAT_WGS + CONF_WGS + MASK_WGS)   // 1152

__device__ __forceinline__ float unnorm_clip(float g, float size) {
    float v = ((g + 1.0f) * size - 1.0f) * 0.5f;
    return fminf(fmaxf(v, 0.0f), size - 1.0f);
}

__device__ __forceinline__ float conf_elem(float logit) {
    float s = logit * (1.0f / 1.5f);
    float e = __expf(-s);
    float p = 1.0f / (1.0f + e);
    float ent = __logf(1.0f + e) + (1.0f - p) * s;
    return 1.0f - ent * 1.4426950408889634f;  // 1/ln2
}

__global__ __launch_bounds__(256) void fused_kernel(
    const float* __restrict__ features,
    const float* __restrict__ mask,
    const float* __restrict__ logits,
    const int*   __restrict__ coords,
    float* __restrict__ out_conf,
    float* __restrict__ out_mask,
    float* __restrict__ out_feat) {

    // 10x10 window x 32 float4 per pixel = 51200 B
    __shared__ f32x4 tile[100 * 32];

    int wg = blockIdx.x;
    int t  = threadIdx.x;

    if (wg < FEAT_WGS) {
        int bk     = wg >> 2;        // patch 0..127
        int dchunk = wg & 3;         // D-chunk: float4s [dchunk*32, dchunk*32+32)
        int b      = bk >> 5;

        float ch = (float)coords[bk * 2 + 0];
        float cw = (float)coords[bk * 2 + 1];
        float fh = ch * 0.125f + 4.0f;   // row center in feature px
        float fw = cw * 0.125f + 4.0f;   // col center in feature px
        // sample x,y always lie in [f-4.5, f+3.5] before clipping -> a 10-px
        // window starting at clamp(floor(f-4.5), 0, 54) covers x0 and x1.
        int r0 = min(max((int)floorf(fh - 4.5f), 0), AGS - 10);
        int c0 = min(max((int)floorf(fw - 4.5f), 0), AGS - 10);

        // ---- stage 100 px x 512B into LDS (8 px per iter, 32 lanes/px) ----
        const f32x4* fsrc = (const f32x4*)(features + (size_t)b * Nn * Dn);
        int lane = t & 31;           // float4 within chunk
        int slot = t >> 5;           // 0..7
        #pragma unroll
        for (int it = 0; it < 13; ++it) {
            int px = it * 8 + slot;
            if (px < 100) {
                int r = px / 10;
                int c = px - r * 10;
                tile[px * 32 + lane] =
                    fsrc[(size_t)((r0 + r) * AGS + (c0 + c)) * 128 + dchunk * 32 + lane];
            }
        }
        __syncthreads();

        // ---- compute: thread = (slot, lane); 32 samples per thread ----
        float cyn = fh * (2.0f / 64.0f) - 1.0f;
        float cxn = fw * (2.0f / 64.0f) - 1.0f;
        f32x4* outp = (f32x4*)out_feat + (size_t)bk * 256 * 128 + dchunk * 32 + lane;

        #pragma unroll 4
        for (int s = 0; s < 32; ++s) {
            int sl = slot + (s << 3);      // sample 0..255
            int i = sl >> 4, j = sl & 15;
            float gx = cxn + (OFF0 + j * OFFSTEP);
            float gy = cyn + (OFF0 + i * OFFSTEP);
            float x = unnorm_clip(gx, 64.0f);
            float y = unnorm_clip(gy, 64.0f);
            float x0f = floorf(x), y0f = floorf(y);
            int x0 = (int)x0f, y0 = (int)y0f;
            int x1 = min(x0 + 1, 63), y1 = min(y0 + 1, 63);
            float wx = x - x0f, wy = y - y0f;
            int xi0 = x0 - c0, xi1 = x1 - c0;
            int yi0 = y0 - r0, yi1 = y1 - r0;

            f32x4 v00 = tile[(yi0 * 10 + xi0) * 32 + lane];
            f32x4 v01 = tile[(yi0 * 10 + xi1) * 32 + lane];
            f32x4 v10 = tile[(yi1 * 10 + xi0) * 32 + lane];
            f32x4 v11 = tile[(yi1 * 10 + xi1) * 32 + lane];

            float w00 = (1.0f - wx) * (1.0f - wy);
            float w01 = wx * (1.0f - wy);
            float w10 = (1.0f - wx) * wy;
            float w11 = wx * wy;
            f32x4 res = v00 * w00 + v01 * w01 + v10 * w10 + v11 * w11;

            outp[(size_t)sl * 128] = res;
        }
        return;
    }

    if (wg < FEAT_WGS + CONF_WGS) {
        // ---- confidence: float4-vectorized elementwise ----
        int tid = (wg - FEAT_WGS) * 256 + t;     // 0..131071
        f32x4 v = ((const f32x4*)logits)[tid];
        f32x4 r;
        r.x = conf_elem(v.x);
        r.y = conf_elem(v.y);
        r.z = conf_elem(v.z);
        r.w = conf_elem(v.w);
        ((f32x4*)out_conf)[tid] = r;
        return;
    }

    {
        // ---- mask patches: one thread per (b,k,i,j) ----
        int idx = (wg - FEAT_WGS - CONF_WGS) * 256 + t;  // 0..32767
        int j  = idx & 15;
        int i  = (idx >> 4) & 15;
        int bk = idx >> 8;
        int bb = bk >> 5;

        float ch = (float)coords[bk * 2 + 0];
        float cw = (float)coords[bk * 2 + 1];
        float cy = (ch + 32.0f) * (2.0f / 512.0f) - 1.0f;
        float cx = (cw + 32.0f) * (2.0f / 512.0f) - 1.0f;
        float gx = cx + (OFF0 + j * OFFSTEP);
        float gy = cy + (OFF0 + i * OFFSTEP);

        float x = unnorm_clip(gx, 512.0f);
        float y = unnorm_clip(gy, 512.0f);
        float x0f = floorf(x), y0f = floorf(y);
        int x0 = (int)x0f, y0 = (int)y0f;
        int x1 = min(x0 + 1, 511), y1 = min(y0 + 1, 511);
        float wx = x - x0f, wy = y - y0f;

        const float* mb = mask + (size_t)bb * RES * RES;
        float v00 = mb[y0 * RES + x0];
        float v01 = mb[y0 * RES + x1];
        float v10 = mb[y1 * RES + x0];
        float v11 = mb[y1 * RES + x1];
        float top = v00 * (1.0f - wx) + v01 * wx;
        float bot = v10 * (1.0f - wx) + v11 * wx;
        float r = top * (1.0f - wy) + bot * wy;
        out_mask[idx] = r;
    }
}

extern "C" void kernel_launch(void* const* d_in, const int* in_sizes, int n_in,
                              void* d_out, int out_size, void* d_ws, size_t ws_size,
                              hipStream_t stream) {
    const float* features = (const float*)d_in[0];
    const float* mask     = (const float*)d_in[1];
    const float* logits   = (const float*)d_in[2];
    const int*   coords   = (const int*)d_in[3];

    float* out_conf = (float*)d_out;                        // B*K*64*64
    float* out_mask = out_conf + (size_t)Bn * Kn * 64 * 64; // B*K*16*16
    float* out_feat = out_mask + (size_t)Bn * Kn * TS * TS; // B*K*256*D

    fused_kernel<<<NWG, 256, 0, stream>>>(
        features, mask, logits, coords, out_conf, out_mask, out_feat);
}